// Round 2
// baseline (244.417 us; speedup 1.0000x reference)
//
#include <hip/hip_runtime.h>
#include <hip/hip_bf16.h>

typedef unsigned short u16;
typedef unsigned int u32;
typedef short bf16x8 __attribute__((ext_vector_type(8)));
typedef float f32x4 __attribute__((ext_vector_type(4)));
typedef u16 u16x8 __attribute__((ext_vector_type(8)));

#define HID 1024
#define BATCH 4096
#define KTOT 2048   // concat K: [x | h_prev]

__device__ __forceinline__ u16 f2bf(float f) {
  u32 v = __builtin_bit_cast(u32, f);
  u32 r = (v + 0x7fffu + ((v >> 16) & 1u)) >> 16;  // round-nearest-even
  return (u16)r;
}
__device__ __forceinline__ float sigmoid_fast(float x) {
  return 1.0f / (1.0f + __expf(-x));
}
__device__ __forceinline__ float tanh_fast(float x) {
  return 2.0f * sigmoid_fast(2.0f * x) - 1.0f;
}
__device__ __forceinline__ void gl_lds16(const void* g, void* l) {
  __builtin_amdgcn_global_load_lds(
      (const __attribute__((address_space(1))) u32*)g,
      (__attribute__((address_space(3))) u32*)l, 16, 0, 0);
}

// ---------------------------------------------------------------------------
// prep_xh: xh[b][k] bf16, k<1024 from x, k>=1024 from h_prev (f32 sources,
// values already bf16-rounded so conversion is lossless). Each thread: one
// 8-element chunk; float4 x2 loads (32B/lane, coalesced), u16x8 store.
// ---------------------------------------------------------------------------
__global__ __launch_bounds__(256) void prep_xh(
    const float* __restrict__ x, const float* __restrict__ hp,
    u16* __restrict__ xh) {
  int c = blockIdx.x * 256 + threadIdx.x;  // chunk id, 8 elems each
  int row = c >> 8;                        // 256 chunks per 2048-col row
  int col0 = (c & 255) << 3;
  const float* src = (col0 < 1024) ? (x + (size_t)row * 1024 + col0)
                                   : (hp + (size_t)row * 1024 + (col0 - 1024));
  f32x4 a = *(const f32x4*)(src);
  f32x4 b = *(const f32x4*)(src + 4);
  u16x8 v;
#pragma unroll
  for (int j = 0; j < 4; ++j) { v[j] = f2bf(a[j]); v[j + 4] = f2bf(b[j]); }
  *(u16x8*)(xh + (size_t)row * KTOT + col0) = v;
}

// ---------------------------------------------------------------------------
// prep_w: build Bt[n'][k] bf16 from f32 weights.
//   n' = (h/16)*64 + g*16 + (h%16)   (64-wide superblock = 16 hcols x 4 gates)
//   k  = which*1024 + ksrc           (which 0 = Wx (x half), 1 = Wh (h half))
// Source W_g[ksrc][h] is [1024,1024] row-major f32. Reads coalesced along h
// (256B/row-segment); writes 16B per lane.
// ---------------------------------------------------------------------------
__global__ __launch_bounds__(256) void prep_w(
    const float* __restrict__ igx, const float* __restrict__ fgx,
    const float* __restrict__ ogx, const float* __restrict__ cgx,
    const float* __restrict__ igu, const float* __restrict__ fgu,
    const float* __restrict__ ogu, const float* __restrict__ cgu,
    u16* __restrict__ bt) {
  const float* srcs[8] = {igx, fgx, ogx, cgx, igu, fgu, ogu, cgu};
  int bid = blockIdx.x;
  int m = bid >> 8;            // matrix 0..7
  int tile = bid & 255;        // 64x64 tile of the 1024x1024 matrix
  int th = tile & 15, tk = tile >> 4;
  int h0 = th << 6, k0 = tk << 6;
  int g = m & 3, which = m >> 2;
  const float* W = srcs[m];

  int t = threadIdx.x;
  int hl = t & 63, cc = t >> 6;
  int h = h0 + hl;
  int np = ((h >> 4) << 6) + (g << 4) + (h & 15);
  size_t dst_row = (size_t)np * KTOT + (size_t)which * 1024;

#pragma unroll
  for (int ci = 0; ci < 2; ++ci) {
    int c = cc + ci * 4;        // k-chunk 0..7 (8 k each)
    int kb = k0 + (c << 3);
    u16x8 v;
#pragma unroll
    for (int j = 0; j < 8; ++j) v[j] = f2bf(W[(size_t)(kb + j) * HID + h]);
    *(u16x8*)(&bt[dst_row + kb]) = v;
  }
}

// ---------------------------------------------------------------------------
// lstm_gemm: 128x128 tile, 4 waves (2x2 of 64x64), 16x16x32 bf16 MFMA,
// global_load_lds width-16 staging, fused LSTM epilogue (f32 in/out).
// Wave's 4 n-tiles are gates i,f,o,c of the same 16 hidden cols.
// ---------------------------------------------------------------------------
__global__ __launch_bounds__(256) void lstm_gemm(
    const u16* __restrict__ xh, const u16* __restrict__ bt,
    const float* __restrict__ cprev,
    const float* __restrict__ ib, const float* __restrict__ fb,
    const float* __restrict__ ob, const float* __restrict__ cb,
    float* __restrict__ hout, float* __restrict__ cout) {
  __shared__ u16 As[128 * 32];
  __shared__ u16 Bs[128 * 32];

  int t = threadIdx.x;
  int brow = blockIdx.x, bcol = blockIdx.y;
  int w = t >> 6, l = t & 63;
  int wr = (w >> 1) * 64, wc = (w & 1) * 64;
  int lrow = l & 15, quad = l >> 4;

  f32x4 acc[4][4] = {};

  int ar0 = t >> 2;            // staging row 0..63 (chunk t), +64 for t+256
  int asub = (t & 3) * 8;      // k offset within 32-wide tile row
  int grow = brow * 128;
  size_t brow_b = (size_t)(bcol * 128);

  for (int kt = 0; kt < 64; ++kt) {
    __syncthreads();
    int kk = kt * 32;
    gl_lds16(xh + (size_t)(grow + ar0) * KTOT + kk + asub, &As[t * 8]);
    gl_lds16(xh + (size_t)(grow + ar0 + 64) * KTOT + kk + asub, &As[(t + 256) * 8]);
    gl_lds16(bt + (brow_b + ar0) * KTOT + kk + asub, &Bs[t * 8]);
    gl_lds16(bt + (brow_b + ar0 + 64) * KTOT + kk + asub, &Bs[(t + 256) * 8]);
    __syncthreads();

    bf16x8 af[4], bfr[4];
#pragma unroll
    for (int i = 0; i < 4; ++i) {
      af[i]  = *(const bf16x8*)&As[(wr + i * 16 + lrow) * 32 + quad * 8];
      bfr[i] = *(const bf16x8*)&Bs[(wc + i * 16 + lrow) * 32 + quad * 8];
    }
#pragma unroll
    for (int mi = 0; mi < 4; ++mi)
#pragma unroll
      for (int ni = 0; ni < 4; ++ni)
        acc[mi][ni] = __builtin_amdgcn_mfma_f32_16x16x32_bf16(
            af[mi], bfr[ni], acc[mi][ni], 0, 0, 0);
  }

  // Epilogue: n-tiles ni = gates i,f,o,c for hidden cols hcol.
  int sb = bcol * 2 + (w & 1);
  int hcol = sb * 16 + lrow;
  float bi = ib[hcol];
  float bff = fb[hcol];
  float bo = ob[hcol];
  float bc = cb[hcol];

#pragma unroll
  for (int mi = 0; mi < 4; ++mi) {
    int row0 = grow + wr + mi * 16 + quad * 4;
#pragma unroll
    for (int r = 0; r < 4; ++r) {
      size_t idx = (size_t)(row0 + r) * HID + hcol;
      float gi = sigmoid_fast(acc[mi][0][r] + bi);
      float gf = sigmoid_fast(acc[mi][1][r] + bff);
      float go = sigmoid_fast(acc[mi][2][r] + bo);
      float gc = tanh_fast(acc[mi][3][r] + bc);
      float cp = cprev[idx];
      float cv = gf * cp + gi * gc;
      float hv = go * tanh_fast(cv);
      hout[idx] = hv;
      cout[idx] = cv;
    }
  }
}

extern "C" void kernel_launch(void* const* d_in, const int* in_sizes, int n_in,
                              void* d_out, int out_size, void* d_ws, size_t ws_size,
                              hipStream_t stream) {
  const float* x   = (const float*)d_in[0];
  const float* hp  = (const float*)d_in[1];
  const float* cp  = (const float*)d_in[2];
  const float* igx = (const float*)d_in[3];
  const float* igu = (const float*)d_in[4];
  const float* ib  = (const float*)d_in[5];
  const float* fgx = (const float*)d_in[6];
  const float* fgu = (const float*)d_in[7];
  const float* fb  = (const float*)d_in[8];
  const float* ogx = (const float*)d_in[9];
  const float* ogu = (const float*)d_in[10];
  const float* ob  = (const float*)d_in[11];
  const float* cgx = (const float*)d_in[12];
  const float* cgu = (const float*)d_in[13];
  const float* cb  = (const float*)d_in[14];

  u16* bt = (u16*)d_ws;                         // [4096][2048] bf16 = 16 MiB
  u16* xh = bt + (size_t)4096 * 2048;           // [4096][2048] bf16 = 16 MiB
  float* hout = (float*)d_out;
  float* cout = hout + (size_t)BATCH * HID;

  prep_xh<<<4096, 256, 0, stream>>>(x, hp, xh);
  prep_w<<<2048, 256, 0, stream>>>(igx, fgx, ogx, cgx, igu, fgu, ogu, cgu, bt);
  lstm_gemm<<<dim3(32, 32), 256, 0, stream>>>(xh, bt, cp, ib, fb, ob, cb,
                                              hout, cout);
}

// Round 3
// 234.566 us; speedup vs baseline: 1.0420x; 1.0420x over previous
//
#include <hip/hip_runtime.h>
#include <hip/hip_bf16.h>

typedef unsigned short u16;
typedef unsigned int u32;
typedef short bf16x8 __attribute__((ext_vector_type(8)));
typedef float f32x4 __attribute__((ext_vector_type(4)));
typedef u16 u16x8 __attribute__((ext_vector_type(8)));

#define HID 1024
#define BATCH 4096
#define KTOT 2048   // concat K: [x | h_prev]

__device__ __forceinline__ u16 f2bf(float f) {
  u32 v = __builtin_bit_cast(u32, f);
  u32 r = (v + 0x7fffu + ((v >> 16) & 1u)) >> 16;  // round-nearest-even
  return (u16)r;
}
__device__ __forceinline__ float sigmoid_fast(float x) {
  return 1.0f / (1.0f + __expf(-x));
}
__device__ __forceinline__ float tanh_fast(float x) {
  return 2.0f * sigmoid_fast(2.0f * x) - 1.0f;
}
__device__ __forceinline__ void gl_lds16(const void* g, void* l) {
  __builtin_amdgcn_global_load_lds(
      (const __attribute__((address_space(1))) u32*)g,
      (__attribute__((address_space(3))) u32*)l, 16, 0, 0);
}

// ---------------------------------------------------------------------------
// prep_xh: xh[b][k] bf16; k<1024 from x, k>=1024 from h_prev (f32 sources,
// values already bf16-rounded). 32B/lane coalesced reads, 16B/lane writes.
// ---------------------------------------------------------------------------
__global__ __launch_bounds__(256) void prep_xh(
    const float* __restrict__ x, const float* __restrict__ hp,
    u16* __restrict__ xh) {
  int c = blockIdx.x * 256 + threadIdx.x;  // chunk id, 8 elems each
  int row = c >> 8;                        // 256 chunks per 2048-col row
  int col0 = (c & 255) << 3;
  const float* src = (col0 < 1024) ? (x + (size_t)row * 1024 + col0)
                                   : (hp + (size_t)row * 1024 + (col0 - 1024));
  f32x4 a = *(const f32x4*)(src);
  f32x4 b = *(const f32x4*)(src + 4);
  u16x8 v;
#pragma unroll
  for (int j = 0; j < 4; ++j) { v[j] = f2bf(a[j]); v[j + 4] = f2bf(b[j]); }
  *(u16x8*)(xh + (size_t)row * KTOT + col0) = v;
}

// ---------------------------------------------------------------------------
// prep_w: build Bt[n'][k] bf16 from f32 weights via 64x64 LDS transpose.
//   n' = (h/16)*64 + g*16 + (h%16), k = which*1024 + ksrc.
// Stage 1: coalesced 256B-segment reads of W rows -> bf16 -> LDS[k][h]
//          (row stride 66 u16 = 33 dwords: +1-dword rotation per row).
// Stage 2: column reads from LDS (conflict-free via rotation), writes where
//          lanes 0..3 cover 64B contiguous of one n' row (full-line segments).
// ---------------------------------------------------------------------------
__global__ __launch_bounds__(256) void prep_w(
    const float* __restrict__ igx, const float* __restrict__ fgx,
    const float* __restrict__ ogx, const float* __restrict__ cgx,
    const float* __restrict__ igu, const float* __restrict__ fgu,
    const float* __restrict__ ogu, const float* __restrict__ cgu,
    u16* __restrict__ bt) {
  __shared__ u16 lds[64 * 66];
  const float* srcs[8] = {igx, fgx, ogx, cgx, igu, fgu, ogu, cgu};
  int bid = blockIdx.x;
  int m = bid >> 8;            // matrix 0..7
  int tile = bid & 255;        // 64x64 tile
  int th = tile & 15, tk = tile >> 4;
  int h0 = th << 6, k0 = tk << 6;
  int g = m & 3, which = m >> 2;
  const float* W = srcs[m] + (size_t)k0 * HID + h0;

  int t = threadIdx.x;

  // stage 1: rows k0..k0+63, cols h0..h0+63
  int r1 = t >> 4;             // 0..15 (row within pass)
  int c1 = (t & 15) << 2;      // 0,4,..,60 (4 floats per thread per pass)
#pragma unroll
  for (int p = 0; p < 4; ++p) {
    int row = (p << 4) + r1;
    f32x4 v = *(const f32x4*)(W + (size_t)row * HID + c1);
    u32 p0 = (u32)f2bf(v[0]) | ((u32)f2bf(v[1]) << 16);
    u32 p1 = (u32)f2bf(v[2]) | ((u32)f2bf(v[3]) << 16);
    u32* d = (u32*)&lds[row * 66 + c1];   // 4B-aligned (132*row + 2*c1)
    d[0] = p0;
    d[1] = p1;
  }
  __syncthreads();

  // stage 2: thread (nl, kc) gathers k-column nl, writes 2x16B to bt
  int nl = t >> 2;             // 0..63 local h
  int kc = t & 3;              // 16B chunk 0..3 (and kc+4)
  int row_np = ((h0 >> 4) << 6) + ((nl >> 4) << 6) + (g << 4) + (nl & 15);
  size_t dst = (size_t)row_np * KTOT + (size_t)which * 1024 + k0;
  u16x8 a, b;
#pragma unroll
  for (int j = 0; j < 8; ++j) {
    a[j] = lds[(kc * 8 + j) * 66 + nl];
    b[j] = lds[(kc * 8 + 32 + j) * 66 + nl];
  }
  *(u16x8*)(&bt[dst + kc * 8]) = a;        // lanes 0..3: 64B contiguous
  *(u16x8*)(&bt[dst + kc * 8 + 32]) = b;
}

// ---------------------------------------------------------------------------
// lstm_gemm: 128x128 tile, 4 waves (2x2 of 64x64), 16x16x32 bf16 MFMA,
// global_load_lds width-16 staging with XOR-swizzled LDS chunks
// (chunk' = chunk ^ ((row>>1)&3)) to kill ds_read_b128 bank conflicts,
// fused LSTM epilogue (f32 in/out).
// ---------------------------------------------------------------------------
__global__ __launch_bounds__(256) void lstm_gemm(
    const u16* __restrict__ xh, const u16* __restrict__ bt,
    const float* __restrict__ cprev,
    const float* __restrict__ ib, const float* __restrict__ fb,
    const float* __restrict__ ob, const float* __restrict__ cb,
    float* __restrict__ hout, float* __restrict__ cout) {
  __shared__ u16 As[128 * 32];
  __shared__ u16 Bs[128 * 32];

  int t = threadIdx.x;
  int brow = blockIdx.x, bcol = blockIdx.y;
  int w = t >> 6, l = t & 63;
  int wr = (w >> 1) * 64, wc = (w & 1) * 64;
  int lrow = l & 15, quad = l >> 4;

  f32x4 acc[4][4] = {};

  // staging: LDS chunk index t holds global chunk (t&3)^((t>>3)&3) of row t>>2
  int srow = t >> 2;                              // 0..63 (+64 second half)
  int schunk = ((t & 3) ^ ((t >> 3) & 3)) << 3;   // swizzled k elem offset
  // fragment reads: global chunk quad of row r lives at LDS chunk quad^s(r),
  // s(r) = (r>>1)&3; within a 16-tile s depends only on lrow.
  int quadp = ((quad ^ ((lrow >> 1) & 3)) << 3);  // elems
  int grow = brow * 128;
  size_t brow_b = (size_t)(bcol * 128);

  for (int kt = 0; kt < 64; ++kt) {
    __syncthreads();
    int kk = kt * 32;
    gl_lds16(xh + (size_t)(grow + srow) * KTOT + kk + schunk, &As[t * 8]);
    gl_lds16(xh + (size_t)(grow + srow + 64) * KTOT + kk + schunk, &As[(t + 256) * 8]);
    gl_lds16(bt + (brow_b + srow) * KTOT + kk + schunk, &Bs[t * 8]);
    gl_lds16(bt + (brow_b + srow + 64) * KTOT + kk + schunk, &Bs[(t + 256) * 8]);
    __syncthreads();

    bf16x8 af[4], bfr[4];
#pragma unroll
    for (int i = 0; i < 4; ++i) {
      af[i]  = *(const bf16x8*)&As[(wr + i * 16 + lrow) * 32 + quadp];
      bfr[i] = *(const bf16x8*)&Bs[(wc + i * 16 + lrow) * 32 + quadp];
    }
#pragma unroll
    for (int mi = 0; mi < 4; ++mi)
#pragma unroll
      for (int ni = 0; ni < 4; ++ni)
        acc[mi][ni] = __builtin_amdgcn_mfma_f32_16x16x32_bf16(
            af[mi], bfr[ni], acc[mi][ni], 0, 0, 0);
  }

  // Epilogue: n-tiles ni = gates i,f,o,c for hidden cols hcol.
  int sb = bcol * 2 + (w & 1);
  int hcol = sb * 16 + lrow;
  float bi = ib[hcol];
  float bff = fb[hcol];
  float bo = ob[hcol];
  float bc = cb[hcol];

#pragma unroll
  for (int mi = 0; mi < 4; ++mi) {
    int row0 = grow + wr + mi * 16 + quad * 4;
#pragma unroll
    for (int r = 0; r < 4; ++r) {
      size_t idx = (size_t)(row0 + r) * HID + hcol;
      float gi = sigmoid_fast(acc[mi][0][r] + bi);
      float gf = sigmoid_fast(acc[mi][1][r] + bff);
      float go = sigmoid_fast(acc[mi][2][r] + bo);
      float gc = tanh_fast(acc[mi][3][r] + bc);
      float cp = cprev[idx];
      float cv = gf * cp + gi * gc;
      float hv = go * tanh_fast(cv);
      hout[idx] = hv;
      cout[idx] = cv;
    }
  }
}

extern "C" void kernel_launch(void* const* d_in, const int* in_sizes, int n_in,
                              void* d_out, int out_size, void* d_ws, size_t ws_size,
                              hipStream_t stream) {
  const float* x   = (const float*)d_in[0];
  const float* hp  = (const float*)d_in[1];
  const float* cp  = (const float*)d_in[2];
  const float* igx = (const float*)d_in[3];
  const float* igu = (const float*)d_in[4];
  const float* ib  = (const float*)d_in[5];
  const float* fgx = (const float*)d_in[6];
  const float* fgu = (const float*)d_in[7];
  const float* fb  = (const float*)d_in[8];
  const float* ogx = (const float*)d_in[9];
  const float* ogu = (const float*)d_in[10];
  const float* ob  = (const float*)d_in[11];
  const float* cgx = (const float*)d_in[12];
  const float* cgu = (const float*)d_in[13];
  const float* cb  = (const float*)d_in[14];

  u16* bt = (u16*)d_ws;                         // [4096][2048] bf16 = 16 MiB
  u16* xh = bt + (size_t)4096 * 2048;           // [4096][2048] bf16 = 16 MiB
  float* hout = (float*)d_out;
  float* cout = hout + (size_t)BATCH * HID;

  prep_xh<<<4096, 256, 0, stream>>>(x, hp, xh);
  prep_w<<<2048, 256, 0, stream>>>(igx, fgx, ogx, cgx, igu, fgu, ogu, cgu, bt);
  lstm_gemm<<<dim3(32, 32), 256, 0, stream>>>(xh, bt, cp, ib, fb, ob, cb,
                                              hout, cout);
}

// Round 4
// 220.459 us; speedup vs baseline: 1.1087x; 1.0640x over previous
//
#include <hip/hip_runtime.h>
#include <hip/hip_bf16.h>

typedef unsigned short u16;
typedef unsigned int u32;
typedef short bf16x8 __attribute__((ext_vector_type(8)));
typedef float f32x4 __attribute__((ext_vector_type(4)));
typedef u16 u16x8 __attribute__((ext_vector_type(8)));

#define HID 1024
#define BATCH 4096
#define KTOT 2048   // concat K: [x | h_prev]

__device__ __forceinline__ u16 f2bf(float f) {
  u32 v = __builtin_bit_cast(u32, f);
  u32 r = (v + 0x7fffu + ((v >> 16) & 1u)) >> 16;  // round-nearest-even
  return (u16)r;
}
__device__ __forceinline__ float sigmoid_fast(float x) {
  return 1.0f / (1.0f + __expf(-x));
}
__device__ __forceinline__ float tanh_fast(float x) {
  return 2.0f * sigmoid_fast(2.0f * x) - 1.0f;
}
__device__ __forceinline__ void gl_lds16(const void* g, void* l) {
  __builtin_amdgcn_global_load_lds(
      (const __attribute__((address_space(1))) u32*)g,
      (__attribute__((address_space(3))) u32*)l, 16, 0, 0);
}

// ---------------------------------------------------------------------------
// prep_xh: xh[b][k] bf16; k<1024 from x, k>=1024 from h_prev (f32 sources,
// values already bf16-rounded). 32B/lane coalesced reads, 16B/lane writes.
// ---------------------------------------------------------------------------
__global__ __launch_bounds__(256) void prep_xh(
    const float* __restrict__ x, const float* __restrict__ hp,
    u16* __restrict__ xh) {
  int c = blockIdx.x * 256 + threadIdx.x;  // chunk id, 8 elems each
  int row = c >> 8;                        // 256 chunks per 2048-col row
  int col0 = (c & 255) << 3;
  const float* src = (col0 < 1024) ? (x + (size_t)row * 1024 + col0)
                                   : (hp + (size_t)row * 1024 + (col0 - 1024));
  f32x4 a = *(const f32x4*)(src);
  f32x4 b = *(const f32x4*)(src + 4);
  u16x8 v;
#pragma unroll
  for (int j = 0; j < 4; ++j) { v[j] = f2bf(a[j]); v[j + 4] = f2bf(b[j]); }
  *(u16x8*)(xh + (size_t)row * KTOT + col0) = v;
}

// ---------------------------------------------------------------------------
// prep_w: build Bt[n'][k] bf16 from f32 weights via 64x64 LDS transpose.
//   n' = (h/16)*64 + g*16 + (h%16), k = which*1024 + ksrc.
// Stage 1: coalesced reads of W rows -> bf16 -> LDS (row stride 66 u16:
//          +1-dword rotation per row -> conflict-free column gather).
// Stage 2: column reads from LDS; writes where lanes 0..3 cover 64B
//          contiguous of one n' row (full-line segments).
// ---------------------------------------------------------------------------
__global__ __launch_bounds__(256) void prep_w(
    const float* __restrict__ igx, const float* __restrict__ fgx,
    const float* __restrict__ ogx, const float* __restrict__ cgx,
    const float* __restrict__ igu, const float* __restrict__ fgu,
    const float* __restrict__ ogu, const float* __restrict__ cgu,
    u16* __restrict__ bt) {
  __shared__ u16 lds[64 * 66];
  const float* srcs[8] = {igx, fgx, ogx, cgx, igu, fgu, ogu, cgu};
  int bid = blockIdx.x;
  int m = bid >> 8;            // matrix 0..7
  int tile = bid & 255;        // 64x64 tile
  int th = tile & 15, tk = tile >> 4;
  int h0 = th << 6, k0 = tk << 6;
  int g = m & 3, which = m >> 2;
  const float* W = srcs[m] + (size_t)k0 * HID + h0;

  int t = threadIdx.x;

  // stage 1: rows k0..k0+63, cols h0..h0+63
  int r1 = t >> 4;             // 0..15 (row within pass)
  int c1 = (t & 15) << 2;      // 0,4,..,60 (4 floats per thread per pass)
#pragma unroll
  for (int p = 0; p < 4; ++p) {
    int row = (p << 4) + r1;
    f32x4 v = *(const f32x4*)(W + (size_t)row * HID + c1);
    u32 p0 = (u32)f2bf(v[0]) | ((u32)f2bf(v[1]) << 16);
    u32 p1 = (u32)f2bf(v[2]) | ((u32)f2bf(v[3]) << 16);
    u32* d = (u32*)&lds[row * 66 + c1];   // 4B-aligned (132*row + 2*c1)
    d[0] = p0;
    d[1] = p1;
  }
  __syncthreads();

  // stage 2: thread (nl, kc) gathers k-column nl, writes 2x16B to bt
  int nl = t >> 2;             // 0..63 local h
  int kc = t & 3;              // 16B chunk 0..3 (and kc+4)
  int row_np = ((h0 >> 4) << 6) + ((nl >> 4) << 6) + (g << 4) + (nl & 15);
  size_t dst = (size_t)row_np * KTOT + (size_t)which * 1024 + k0;
  u16x8 a, b;
#pragma unroll
  for (int j = 0; j < 8; ++j) {
    a[j] = lds[(kc * 8 + j) * 66 + nl];
    b[j] = lds[(kc * 8 + 32 + j) * 66 + nl];
  }
  *(u16x8*)(&bt[dst + kc * 8]) = a;        // lanes 0..3: 64B contiguous
  *(u16x8*)(&bt[dst + kc * 8 + 32]) = b;
}

// ---------------------------------------------------------------------------
// lstm_gemm: 128x128 tile, 4 waves (2x2 of 64x64), 16x16x32 bf16 MFMA.
// BK=64 per iteration: two 32-k subtiles staged per barrier pair (32 iters
// instead of 64 -> half the barrier drains). 32 KB LDS single-buffered.
// global_load_lds width-16 staging with XOR-swizzled chunks
// (chunk' = chunk ^ ((row>>1)&3)) -> zero ds_read_b128 bank conflicts.
// Fused LSTM epilogue (f32 in/out).
// ---------------------------------------------------------------------------
__global__ __launch_bounds__(256) void lstm_gemm(
    const u16* __restrict__ xh, const u16* __restrict__ bt,
    const float* __restrict__ cprev,
    const float* __restrict__ ib, const float* __restrict__ fb,
    const float* __restrict__ ob, const float* __restrict__ cb,
    float* __restrict__ hout, float* __restrict__ cout) {
  __shared__ u16 As[2 * 128 * 32];   // two 32-k subtiles
  __shared__ u16 Bs[2 * 128 * 32];

  int t = threadIdx.x;
  int brow = blockIdx.x, bcol = blockIdx.y;
  int w = t >> 6, l = t & 63;
  int wr = (w >> 1) * 64, wc = (w & 1) * 64;
  int lrow = l & 15, quad = l >> 4;

  f32x4 acc[4][4] = {};

  // staging: LDS chunk index t holds global chunk (t&3)^((t>>3)&3) of row t>>2
  int srow = t >> 2;                              // 0..63 (+64 second half)
  int schunk = ((t & 3) ^ ((t >> 3) & 3)) << 3;   // swizzled k elem offset
  // fragment reads: global chunk quad of row r lives at LDS chunk quad^s(r)
  int quadp = ((quad ^ ((lrow >> 1) & 3)) << 3);  // elems
  int grow = brow * 128;
  size_t brow_b = (size_t)(bcol * 128);

  const u16* arow0 = xh + (size_t)(grow + srow) * KTOT + schunk;
  const u16* arow1 = xh + (size_t)(grow + srow + 64) * KTOT + schunk;
  const u16* brow0 = bt + (brow_b + srow) * KTOT + schunk;
  const u16* brow1 = bt + (brow_b + srow + 64) * KTOT + schunk;

  for (int kt = 0; kt < 32; ++kt) {
    __syncthreads();
    int kk = kt * 64;
    gl_lds16(arow0 + kk, &As[t * 8]);
    gl_lds16(arow1 + kk, &As[(t + 256) * 8]);
    gl_lds16(arow0 + kk + 32, &As[4096 + t * 8]);
    gl_lds16(arow1 + kk + 32, &As[4096 + (t + 256) * 8]);
    gl_lds16(brow0 + kk, &Bs[t * 8]);
    gl_lds16(brow1 + kk, &Bs[(t + 256) * 8]);
    gl_lds16(brow0 + kk + 32, &Bs[4096 + t * 8]);
    gl_lds16(brow1 + kk + 32, &Bs[4096 + (t + 256) * 8]);
    __syncthreads();

#pragma unroll
    for (int s = 0; s < 2; ++s) {
      int base = s * 4096;
      bf16x8 af[4], bfr[4];
#pragma unroll
      for (int i = 0; i < 4; ++i) {
        af[i]  = *(const bf16x8*)&As[base + (wr + i * 16 + lrow) * 32 + quadp];
        bfr[i] = *(const bf16x8*)&Bs[base + (wc + i * 16 + lrow) * 32 + quadp];
      }
#pragma unroll
      for (int mi = 0; mi < 4; ++mi)
#pragma unroll
        for (int ni = 0; ni < 4; ++ni)
          acc[mi][ni] = __builtin_amdgcn_mfma_f32_16x16x32_bf16(
              af[mi], bfr[ni], acc[mi][ni], 0, 0, 0);
    }
  }

  // Epilogue: n-tiles ni = gates i,f,o,c for hidden cols hcol.
  int sb = bcol * 2 + (w & 1);
  int hcol = sb * 16 + lrow;
  float bi = ib[hcol];
  float bff = fb[hcol];
  float bo = ob[hcol];
  float bc = cb[hcol];

#pragma unroll
  for (int mi = 0; mi < 4; ++mi) {
    int row0 = grow + wr + mi * 16 + quad * 4;
#pragma unroll
    for (int r = 0; r < 4; ++r) {
      size_t idx = (size_t)(row0 + r) * HID + hcol;
      float gi = sigmoid_fast(acc[mi][0][r] + bi);
      float gf = sigmoid_fast(acc[mi][1][r] + bff);
      float go = sigmoid_fast(acc[mi][2][r] + bo);
      float gc = tanh_fast(acc[mi][3][r] + bc);
      float cp = cprev[idx];
      float cv = gf * cp + gi * gc;
      float hv = go * tanh_fast(cv);
      hout[idx] = hv;
      cout[idx] = cv;
    }
  }
}

extern "C" void kernel_launch(void* const* d_in, const int* in_sizes, int n_in,
                              void* d_out, int out_size, void* d_ws, size_t ws_size,
                              hipStream_t stream) {
  const float* x   = (const float*)d_in[0];
  const float* hp  = (const float*)d_in[1];
  const float* cp  = (const float*)d_in[2];
  const float* igx = (const float*)d_in[3];
  const float* igu = (const float*)d_in[4];
  const float* ib  = (const float*)d_in[5];
  const float* fgx = (const float*)d_in[6];
  const float* fgu = (const float*)d_in[7];
  const float* fb  = (const float*)d_in[8];
  const float* ogx = (const float*)d_in[9];
  const float* ogu = (const float*)d_in[10];
  const float* ob  = (const float*)d_in[11];
  const float* cgx = (const float*)d_in[12];
  const float* cgu = (const float*)d_in[13];
  const float* cb  = (const float*)d_in[14];

  u16* bt = (u16*)d_ws;                         // [4096][2048] bf16 = 16 MiB
  u16* xh = bt + (size_t)4096 * 2048;           // [4096][2048] bf16 = 16 MiB
  float* hout = (float*)d_out;
  float* cout = hout + (size_t)BATCH * HID;

  prep_xh<<<4096, 256, 0, stream>>>(x, hp, xh);
  prep_w<<<2048, 256, 0, stream>>>(igx, fgx, ogx, cgx, igu, fgu, ogu, cgu, bt);
  lstm_gemm<<<dim3(32, 32), 256, 0, stream>>>(xh, bt, cp, ib, fb, ob, cb,
                                              hout, cout);
}